// Round 2
// baseline (480.424 us; speedup 1.0000x reference)
//
#include <hip/hip_runtime.h>
#include <math.h>

#define L_SIG 65537
#define NH    65536     // half-size complex FFT length (NFFT/2)
#define NSIG  256
#define PI_F  3.14159265358979323846f
#define STR   258       // LDS row stride (c32 / float units) for k_fused

struct c32 { float x, y; };
__device__ __forceinline__ c32 mkc(float a, float b){ c32 r; r.x=a; r.y=b; return r; }
__device__ __forceinline__ c32 cadd(c32 a, c32 b){ return mkc(a.x+b.x, a.y+b.y); }
__device__ __forceinline__ c32 csub(c32 a, c32 b){ return mkc(a.x-b.x, a.y-b.y); }
__device__ __forceinline__ c32 cmul(c32 a, c32 b){ return mkc(a.x*b.x - a.y*b.y, a.x*b.y + a.y*b.x); }

// ---------------- 16-point FFT in registers (radix-4 x 2) ------------------
template<int S>
__device__ __forceinline__ void fft16(c32 v[16]) {
  constexpr float C16[16] = {
    1.0f, 0.9238795325112867f, 0.7071067811865476f, 0.3826834323650898f,
    0.0f,-0.3826834323650898f,-0.7071067811865476f,-0.9238795325112867f,
   -1.0f,-0.9238795325112867f,-0.7071067811865476f,-0.3826834323650898f,
    0.0f, 0.3826834323650898f, 0.7071067811865476f, 0.9238795325112867f };
  constexpr float S16[16] = {
    0.0f, 0.3826834323650898f, 0.7071067811865476f, 0.9238795325112867f,
    1.0f, 0.9238795325112867f, 0.7071067811865476f, 0.3826834323650898f,
    0.0f,-0.3826834323650898f,-0.7071067811865476f,-0.9238795325112867f,
   -1.0f,-0.9238795325112867f,-0.7071067811865476f,-0.3826834323650898f };
  c32 s[16];
  #pragma unroll
  for (int b0 = 0; b0 < 4; ++b0) {
    c32 x0=v[b0], x1=v[b0+4], x2=v[b0+8], x3=v[b0+12];
    c32 u0=cadd(x0,x2), u1=csub(x0,x2), u2=cadd(x1,x3), u3=csub(x1,x3);
    c32 iu3 = mkc(-u3.y, u3.x);
    c32 yy[4];
    yy[0]=cadd(u0,u2); yy[2]=csub(u0,u2);
    if (S < 0) { yy[1]=csub(u1,iu3); yy[3]=cadd(u1,iu3); }
    else       { yy[1]=cadd(u1,iu3); yy[3]=csub(u1,iu3); }
    #pragma unroll
    for (int c0 = 0; c0 < 4; ++c0) {
      const int p = (b0*c0) & 15;
      c32 w = mkc(C16[p], (S<0) ? -S16[p] : S16[p]);
      s[c0*4 + b0] = cmul(yy[c0], w);
    }
  }
  #pragma unroll
  for (int c0 = 0; c0 < 4; ++c0) {
    c32 x0=s[c0*4+0], x1=s[c0*4+1], x2=s[c0*4+2], x3=s[c0*4+3];
    c32 u0=cadd(x0,x2), u1=csub(x0,x2), u2=cadd(x1,x3), u3=csub(x1,x3);
    c32 iu3 = mkc(-u3.y, u3.x);
    c32 yy[4];
    yy[0]=cadd(u0,u2); yy[2]=csub(u0,u2);
    if (S < 0) { yy[1]=csub(u1,iu3); yy[3]=cadd(u1,iu3); }
    else       { yy[1]=cadd(u1,iu3); yy[3]=csub(u1,iu3); }
    v[c0+0]=yy[0]; v[c0+4]=yy[1]; v[c0+8]=yy[2]; v[c0+12]=yy[3];
  }
}

// ---------------- 256-pt FFT, 16-thread team, block-wide scratch ----------
template<int S>
__device__ __forceinline__ void fft256_team(c32 v[16], int r, int t, c32* sm) {
  fft16<S>(v);
  float ang = (float)S * (2.0f*PI_F/256.0f) * (float)r;
  c32 st; __sincosf(ang, &st.y, &st.x);
  c32 w = st;
  #pragma unroll
  for (int c = 1; c < 16; ++c) { v[c] = cmul(v[c], w); w = cmul(w, st); }
  __syncthreads();
  #pragma unroll
  for (int c = 0; c < 16; ++c) sm[c*256 + r*16 + t] = v[c];
  __syncthreads();
  #pragma unroll
  for (int a = 0; a < 16; ++a) v[a] = sm[r*256 + a*16 + t];
  fft16<S>(v);
}

// ---------------- 256-pt FFT using the team's own LDS row as scratch ------
// All 256 threads MUST call (contains __syncthreads); inactive teams pass act=false.
template<int S>
__device__ __forceinline__ void fft256_row(c32 v[16], int r, c32* row, bool act) {
  if (act) {
    fft16<S>(v);
    float ang = (float)S * (2.0f*PI_F/256.0f) * (float)r;
    c32 st; __sincosf(ang, &st.y, &st.x);
    c32 w = st;
    #pragma unroll
    for (int c = 1; c < 16; ++c) { v[c] = cmul(v[c], w); w = cmul(w, st); }
  }
  __syncthreads();
  if (act) {
    #pragma unroll
    for (int c = 0; c < 16; ++c) row[c*16 + r] = v[c];
  }
  __syncthreads();
  if (act) {
    #pragma unroll
    for (int a = 0; a < 16; ++a) v[a] = row[r*16 + a];
    fft16<S>(v);
  }
}

__device__ __forceinline__ int colof(int q, int s) {
  return (s < 10) ? ((8*q - 1 + s) & 255) : ((248 - 8*q + (s - 10)) & 255);
}

// X[k] = 0.5(zk + conj(zb)) - 0.5 i W^k (zk - conj(zb)), W = e^{-i pi/65536}
__device__ __forceinline__ c32 unpackZ(c32 zk, c32 zb, float k) {
  c32 Aa = mkc(0.5f*(zk.x + zb.x), 0.5f*(zk.y - zb.y));
  c32 Bm = mkc(0.5f*(zk.x - zb.x), 0.5f*(zk.y + zb.y));
  float sw, cw; __sincosf(-(PI_F/65536.0f) * k, &sw, &cw);
  c32 miw = mkc(sw, -cw);                 // -i * W^k
  return cadd(Aa, cmul(miw, Bm));
}

// ---------------- prep: mod_depth, pm, spectral line table ----------------
__global__ __launch_bounds__(256) void k_prep(const float* __restrict__ b1,
    const float* __restrict__ W2, const float* __restrict__ b2,
    const float* __restrict__ W3, const float* __restrict__ b3,
    const float* __restrict__ hp, const float* __restrict__ fw,
    float* __restrict__ pm_out, int* __restrict__ hidx, float* __restrict__ amp) {
  __shared__ float red[256];
  __shared__ float s_md, s_pm;
  int t = threadIdx.x;
  if (t == 0) {
    float h1[32], h2[16];
    for (int i=0;i<32;i++){ float z = b1[i]; h1[i] = z > 0.f ? z : 0.f; }
    for (int o=0;o<16;o++){ float acc = b2[o];
      for (int i=0;i<32;i++) acc += h1[i]*W2[i*16+o];
      h2[o] = acc > 0.f ? acc : 0.f; }
    float md = b3[1];
    for (int i=0;i<16;i++) md += h2[i]*W3[i*8+1];
    s_md = md;
  }
  __syncthreads();
  float md = s_md;
  float partial = 0.f;
  for (int tt = t; tt < 65537; tt += 256) {
    int ci = (tt * 8) / 65537;
    float cs = hp[ci*4+0] + hp[ci*4+1] + hp[ci*4+2] + hp[ci*4+3];
    float ang = (6.2831853071795864769f * (float)tt) / 65537.0f;
    partial += cs * (1.f + md * sinf(ang));
  }
  red[t] = partial;
  __syncthreads();
  for (int s = 128; s > 0; s >>= 1) { if (t < s) red[t] += red[t+s]; __syncthreads(); }
  if (t == 0) { s_pm = red[0] / (65537.0f * 4.0f); pm_out[0] = s_pm; }
  __syncthreads();
  if (t < 40) {
    const double SPECF[8] = {7.83, 528.0, 396.0, 2.5, 14.1, 432.0, 6.0, 30.0};
    int j = t / 5, mi = t % 5;
    double mult = (double)(mi + 1);
    double hf = SPECF[j] * mult;
    double ratio = hf * (131072.0 / 22050.0);
    hidx[t] = (int)floor(ratio + 0.5);
    amp[t] = (float)((double)fw[j] * pow(mult, -1.2) * (1.0 + (double)s_pm));
  }
}

// ---------------- gain curve -> transposed layout gain_t[c*257 + k1] ------
__global__ __launch_bounds__(256) void k_gain(float* __restrict__ gain_t,
    const float* __restrict__ bw, const int* __restrict__ hidx,
    const float* __restrict__ amp) {
  int i = blockIdx.x*256 + threadIdx.x;
  if (i >= 65537) return;
  float f = (float)((double)i * (22050.0/131072.0));
  float g = 1.0f;
  constexpr double LO[6] = {1,4,8,13,30,100};
  constexpr double HI[6] = {4,8,13,30,100,200};
  #pragma unroll
  for (int k = 0; k < 6; ++k) {
    float center = (float)(0.5*(LO[k]+HI[k]));
    float sig    = (float)(0.25*(HI[k]-LO[k]));
    float dm = (f - center)/sig;
    float mask = expf(-0.5f*dm*dm);
    if (f < (float)LO[k] || f > (float)HI[k]) mask = 0.f;
    float ang = (float)(6.283185307179586*0.5*(LO[k]+HI[k])) * (float)i / 22050.0f;
    g *= 1.0f + mask * bw[k] * (1.0f + 0.2f*sinf(ang));
  }
  for (int l = 0; l < 40; ++l) {
    int d = i - hidx[l];
    if (d >= -15 && d <= 15) {
      float dd = (float)d * 0.2f;
      g *= 1.0f + amp[l] * expf(-0.5f*dd*dd);
    }
  }
  int c = i & 255, k1 = i >> 8;        // i == c + 256*k1; i=65536 -> (0,256)
  gain_t[c*257 + k1] = g;
}

// ---------------- forward pass 1: pack + column FFT + 4-step twiddle ------
__global__ __launch_bounds__(256) void k_fwd1(const float* __restrict__ x,
                                              c32* __restrict__ A, int s0) {
  __shared__ c32 sm[4112];
  int b = blockIdx.x; int sl = b >> 4; int g = b & 15;
  int t = threadIdx.x & 15, r = threadIdx.x >> 4;
  int n1 = g*16 + t;
  const float* xb = x + (size_t)(s0 + sl) * L_SIG;
  c32 v[16];
  #pragma unroll
  for (int j = 0; j < 16; ++j) {
    int n = n1 + 256*r + 4096*j;
    c32 z = mkc(0.f, 0.f);
    if (n < 32768)       { z.x = xb[2*n]; z.y = xb[2*n+1]; }
    else if (n == 32768) { z.x = xb[65536]; }
    v[j] = z;
  }
  fft256_team<-1>(v, r, t, sm);
  float a0 = -(2.0f*PI_F/65536.0f) * (float)(n1 * r);
  float a1 = -(2.0f*PI_F/4096.0f)  * (float)n1;
  c32 wb, wst;
  __sincosf(a0, &wb.y, &wb.x);
  __sincosf(a1, &wst.y, &wst.x);
  #pragma unroll
  for (int j = 0; j < 16; ++j) { v[j] = cmul(v[j], wb); wb = cmul(wb, wst); }
  __syncthreads();
  #pragma unroll
  for (int j = 0; j < 16; ++j) sm[(r + 16*j)*16 + t] = v[j];
  __syncthreads();
  c32* Ab = A + (size_t)sl * NH;
  int u = threadIdx.x & 15, k2b = threadIdx.x >> 4;
  #pragma unroll
  for (int m = 0; m < 16; ++m) {
    int k2 = k2b + 16*m;
    Ab[(size_t)k2*256 + g*16 + u] = sm[k2*16 + u];
  }
}

// ---------------- fused: row FFT + unpack/gain/smooth/repack + inv col FFT
// Block q in [0,16) per signal owns k2 columns [8q,8q+7] and mirrors.
__global__ __launch_bounds__(256) void k_fused(const c32* __restrict__ A,
    c32* __restrict__ Bp, const float* __restrict__ gain_t) {
  __shared__ c32   ZC[20*STR];      // 41280 B : Z cols / FFT scratch / Zc cols
  __shared__ float MAG[20*STR];     // 20640 B
  __shared__ int   colslot[256];    // 1024 B
  int b = blockIdx.x; int sl = b >> 4; int q = b & 15;
  int tid = threadIdx.x;
  int r = tid >> 4, t = tid & 15;
  const c32* Ab = A + (size_t)sl * NH;
  c32* Bb = Bp + (size_t)sl * NH;

  if (tid < 20) colslot[colof(q, tid)] = tid;   // dup-col races benign (identical data)
  // stage 20 A-columns (contiguous 2 KB each) into ZC rows
  for (int m = 0; m < 20; ++m)
    ZC[m*STR + tid] = Ab[(size_t)colof(q, m)*256 + tid];
  __syncthreads();

  // ---- forward row FFTs over n1 -> Z[col][k1], in place, 2 rounds -------
  for (int base = 0; base < 20; base += 16) {
    int slot = base + t;
    bool act = slot < 20;
    int ss = act ? slot : 0;
    c32 v[16];
    if (act) {
      #pragma unroll
      for (int j = 0; j < 16; ++j) v[j] = ZC[ss*STR + r + 16*j];
    }
    fft256_row<-1>(v, r, ZC + ss*STR, act);
    __syncthreads();
    if (act) {
      #pragma unroll
      for (int j = 0; j < 16; ++j) ZC[ss*STR + r + 16*j] = v[j];
    }
    __syncthreads();
  }

  // ---- phase 1: magnitudes for all 20 columns ---------------------------
  {
    int k1 = tid;
    for (int s = 0; s < 20; ++s) {
      int c = colof(q, s);
      int ms = 19 - s;
      int mz = (c == 0) ? ((256 - k1) & 255) : (255 - k1);
      int k = c + 256*k1;
      c32 zk = ZC[s*STR + k1];
      c32 zb = ZC[ms*STR + mz];
      c32 X = unpackZ(zk, zb, (float)k);
      float g = gain_t[c*257 + k1];
      X.x *= g; X.y *= g;
      MAG[s*STR + k1] = sqrtf(X.x*X.x + X.y*X.y);
    }
    if (tid < 20 && colof(q, tid) == 0) {       // pseudo bin k=65536 (q==0 only)
      c32 z0 = ZC[tid*STR + 0];
      c32 X = unpackZ(z0, z0, 65536.0f);
      float g = gain_t[256];
      X.x *= g; X.y *= g;
      MAG[tid*STR + 256] = sqrtf(X.x*X.x + X.y*X.y);
    }
  }
  __syncthreads();

  // ---- phase 2: smooth + repack, in place on ZC -------------------------
  {
    const float invN = 1.0f/65536.0f;
    int k1 = tid;
    for (int l = 1; l <= 8; ++l) {
      int cL = 8*q + l - 1;
      bool sp0 = (cL == 0);                   // q==0, l==1: column 0 self-pair
      if (sp0 && k1 > 128) continue;
      int sL = l;
      int sH = sp0 ? l : (19 - l);            // write slot for H side
      int cH = (256 - cL) & 255;
      int mI = sp0 ? (256 - k1) : (255 - k1); // gain row index (may be 256)
      int mz = mI & 255;
      int k = cL + 256*k1;
      int K = 65536 - k;
      c32 zL = ZC[sL*STR + k1];
      c32 zH = ZC[(sp0 ? 18 : sH)*STR + mz];  // slot 18 = dup col-0 (read-only)
      float gk = gain_t[cL*257 + k1];
      float gK = gain_t[cH*257 + mI];
      c32 XgL = unpackZ(zL, zH, (float)k);  XgL.x *= gk; XgL.y *= gk;
      c32 XgH = unpackZ(zH, zL, (float)K);  XgH.x *= gK; XgH.y *= gK;
      float mL = sqrtf(XgL.x*XgL.x + XgL.y*XgL.y);
      float mH = sqrtf(XgH.x*XgH.x + XgH.y*XgH.y);
      float msL = (k == 0) ? mL
        : 0.7f*mL + 0.15f*(MAG[colslot[(k-1)&255]*STR + ((k-1)>>8)]
                         + MAG[colslot[(k+1)&255]*STR + ((k+1)>>8)]);
      float msH = (K == 65536) ? mH
        : 0.7f*mH + 0.15f*(MAG[colslot[(K-1)&255]*STR + ((K-1)>>8)]
                         + MAG[colslot[(K+1)&255]*STR + ((K+1)>>8)]);
      c32 XcL = (mL > 0.f) ? mkc(XgL.x*(msL/mL), XgL.y*(msL/mL)) : mkc(msL, 0.f);
      c32 XcH = (mH > 0.f) ? mkc(XgH.x*(msH/mH), XgH.y*(msH/mH)) : mkc(msH, 0.f);
      c32 E = mkc(0.5f*(XcL.x + XcH.x), 0.5f*(XcL.y - XcH.y));
      c32 D = mkc(0.5f*(XcL.x - XcH.x), 0.5f*(XcL.y + XcH.y));
      float so, co; __sincosf((PI_F/65536.0f)*(float)k, &so, &co);
      c32 O = cmul(mkc(co, so), D);
      ZC[sL*STR + k1] = mkc((E.x - O.y)*invN, (E.y + O.x)*invN);
      if (!(sp0 && k1 == 0))
        ZC[sH*STR + mz] = mkc((E.x + O.y)*invN, (O.x - E.y)*invN);
    }
    if (q == 15 && k1 < 128) {               // column 128 self-pair
      int mz = 255 - k1;
      int k = 128 + 256*k1;
      int K = 65536 - k;                     // = 128 + 256*mz
      c32 zL = ZC[9*STR + k1];
      c32 zH = ZC[10*STR + mz];              // dup col-128 (read-only)
      float gk = gain_t[128*257 + k1];
      float gK = gain_t[128*257 + mz];
      c32 XgL = unpackZ(zL, zH, (float)k);  XgL.x *= gk; XgL.y *= gk;
      c32 XgH = unpackZ(zH, zL, (float)K);  XgH.x *= gK; XgH.y *= gK;
      float mL = sqrtf(XgL.x*XgL.x + XgL.y*XgL.y);
      float mH = sqrtf(XgH.x*XgH.x + XgH.y*XgH.y);
      float msL = 0.7f*mL + 0.15f*(MAG[colslot[(k-1)&255]*STR + ((k-1)>>8)]
                                 + MAG[colslot[(k+1)&255]*STR + ((k+1)>>8)]);
      float msH = 0.7f*mH + 0.15f*(MAG[colslot[(K-1)&255]*STR + ((K-1)>>8)]
                                 + MAG[colslot[(K+1)&255]*STR + ((K+1)>>8)]);
      c32 XcL = (mL > 0.f) ? mkc(XgL.x*(msL/mL), XgL.y*(msL/mL)) : mkc(msL, 0.f);
      c32 XcH = (mH > 0.f) ? mkc(XgH.x*(msH/mH), XgH.y*(msH/mH)) : mkc(msH, 0.f);
      c32 E = mkc(0.5f*(XcL.x + XcH.x), 0.5f*(XcL.y - XcH.y));
      c32 D = mkc(0.5f*(XcL.x - XcH.x), 0.5f*(XcL.y + XcH.y));
      float so, co; __sincosf((PI_F/65536.0f)*(float)k, &so, &co);
      c32 O = cmul(mkc(co, so), D);
      ZC[9*STR + k1] = mkc((E.x - O.y)*invN, (E.y + O.x)*invN);
      ZC[9*STR + mz] = mkc((E.x + O.y)*invN, (O.x - E.y)*invN);
    }
  }
  __syncthreads();

  // ---- inverse first-stage FFT over k1 + twiddle + coalesced B' write ----
  int ncols = (q == 0) ? 15 : ((q == 15) ? 17 : 16);
  for (int base = 0; base < ncols; base += 16) {
    int idx = base + t;
    bool act = idx < ncols;
    int slot = (idx < 8) ? (1 + idx) : ((idx < 16) ? (3 + idx) : 9);
    if (!act) slot = 0;
    int a = colof(q, slot);
    c32 v[16];
    if (act) {
      #pragma unroll
      for (int j = 0; j < 16; ++j) v[j] = ZC[slot*STR + r + 16*j];
    }
    fft256_row<1>(v, r, ZC + slot*STR, act);
    if (act) {
      float a0 = (2.0f*PI_F/65536.0f) * (float)(a * r);
      float a1 = (2.0f*PI_F/4096.0f)  * (float)a;
      c32 wb, wst;
      __sincosf(a0, &wb.y, &wb.x);
      __sincosf(a1, &wst.y, &wst.x);
      #pragma unroll
      for (int j = 0; j < 16; ++j) {
        c32 o = cmul(v[j], wb); wb = cmul(wb, wst);
        Bb[(size_t)a*256 + r + 16*j] = o;     // B'[a][m2], contiguous per column
      }
    }
    __syncthreads();
  }
}

// ---------------- inverse pass 2: reads B'[a*256+m2], FFT over a ----------
__global__ __launch_bounds__(256) void k_inv2t(const c32* __restrict__ Bp,
                                               float* __restrict__ out, int s0) {
  __shared__ c32 sm[4112];
  int b = blockIdx.x; int sl = b >> 4; int g = b & 15;
  int t = threadIdx.x & 15, r = threadIdx.x >> 4;
  const c32* Bb = Bp + (size_t)sl * NH;
  #pragma unroll
  for (int m = 0; m < 16; ++m) {
    int flat = threadIdx.x + 256*m;
    int a = flat >> 4, mo = flat & 15;
    sm[mo*257 + a] = Bb[(size_t)a*256 + 16*g + mo];
  }
  __syncthreads();
  c32 v[16];
  #pragma unroll
  for (int j = 0; j < 16; ++j) v[j] = sm[t*257 + r + 16*j];
  fft256_team<1>(v, r, t, sm);
  float* yb = out + (size_t)(s0 + sl) * L_SIG;
  int m2 = g*16 + t;                  // fast final index
  #pragma unroll
  for (int j = 0; j < 16; ++j) {
    int m1 = r + 16*j;                // slow final index
    if (m1 <= 127) {
      int m = m2 + 256*m1;
      yb[2*m]   = v[j].x;
      yb[2*m+1] = v[j].y;
    } else if (m1 == 128 && m2 == 0) {
      yb[65536] = v[j].x;
    }
  }
}

// --------------------------------------------------------------------------
extern "C" void kernel_launch(void* const* d_in, const int* in_sizes, int n_in,
                              void* d_out, int out_size, void* d_ws, size_t ws_size,
                              hipStream_t stream) {
  const float* x  = (const float*)d_in[0];
  const float* bw = (const float*)d_in[1];
  const float* fw = (const float*)d_in[2];
  const float* hp = (const float*)d_in[3];
  // d_in[4] = W1: mathematically unused (tn==0 at the only sampled row)
  const float* b1 = (const float*)d_in[5];
  const float* W2 = (const float*)d_in[6];
  const float* b2 = (const float*)d_in[7];
  const float* W3 = (const float*)d_in[8];
  const float* b3 = (const float*)d_in[9];
  float* out = (float*)d_out;
  char* ws = (char*)d_ws;

  const size_t perSig = (size_t)NH * sizeof(c32);            // 512 KiB / signal / buffer
  const size_t tail   = (size_t)66048 * sizeof(float) + 512; // gain_t + scalars
  size_t cap = (ws_size > tail) ? (ws_size - tail) / (2*perSig) : 1;
  int chunk = (cap >= (size_t)NSIG) ? NSIG : (cap < 1 ? 1 : (int)cap);

  c32*   A      = (c32*)ws;
  c32*   Bb     = (c32*)(ws + (size_t)chunk*perSig);
  float* gain_t = (float*)(ws + 2*(size_t)chunk*perSig);
  float* pm     = gain_t + 66048;
  int*   hidx   = (int*)(pm + 1);
  float* amp    = (float*)(hidx + 40);

  k_prep<<<1, 256, 0, stream>>>(b1, W2, b2, W3, b3, hp, fw, pm, hidx, amp);
  k_gain<<<257, 256, 0, stream>>>(gain_t, bw, hidx, amp);

  for (int s0 = 0; s0 < NSIG; s0 += chunk) {
    int S = (NSIG - s0 < chunk) ? (NSIG - s0) : chunk;
    k_fwd1 <<<S*16, 256, 0, stream>>>(x, A, s0);
    k_fused<<<S*16, 256, 0, stream>>>(A, Bb, gain_t);
    k_inv2t<<<S*16, 256, 0, stream>>>(Bb, out, s0);
  }
}

// Round 3
// 436.414 us; speedup vs baseline: 1.1008x; 1.1008x over previous
//
#include <hip/hip_runtime.h>
#include <math.h>

#define L_SIG 65537
#define NH    65536     // half-size complex FFT length (NFFT/2)
#define NSIG  256
#define PI_F  3.14159265358979323846f

struct c32 { float x, y; };
__device__ __forceinline__ c32 mkc(float a, float b){ c32 r; r.x=a; r.y=b; return r; }
__device__ __forceinline__ c32 cadd(c32 a, c32 b){ return mkc(a.x+b.x, a.y+b.y); }
__device__ __forceinline__ c32 csub(c32 a, c32 b){ return mkc(a.x-b.x, a.y-b.y); }
__device__ __forceinline__ c32 cmul(c32 a, c32 b){ return mkc(a.x*b.x - a.y*b.y, a.x*b.y + a.y*b.x); }

// ---------------- 16-point FFT in registers (radix-4 x 2) ------------------
template<int S>
__device__ __forceinline__ void fft16(c32 v[16]) {
  constexpr float C16[16] = {
    1.0f, 0.9238795325112867f, 0.7071067811865476f, 0.3826834323650898f,
    0.0f,-0.3826834323650898f,-0.7071067811865476f,-0.9238795325112867f,
   -1.0f,-0.9238795325112867f,-0.7071067811865476f,-0.3826834323650898f,
    0.0f, 0.3826834323650898f, 0.7071067811865476f, 0.9238795325112867f };
  constexpr float S16[16] = {
    0.0f, 0.3826834323650898f, 0.7071067811865476f, 0.9238795325112867f,
    1.0f, 0.9238795325112867f, 0.7071067811865476f, 0.3826834323650898f,
    0.0f,-0.3826834323650898f,-0.7071067811865476f,-0.9238795325112867f,
   -1.0f,-0.9238795325112867f,-0.7071067811865476f,-0.3826834323650898f };
  c32 s[16];
  #pragma unroll
  for (int b0 = 0; b0 < 4; ++b0) {
    c32 x0=v[b0], x1=v[b0+4], x2=v[b0+8], x3=v[b0+12];
    c32 u0=cadd(x0,x2), u1=csub(x0,x2), u2=cadd(x1,x3), u3=csub(x1,x3);
    c32 iu3 = mkc(-u3.y, u3.x);
    c32 yy[4];
    yy[0]=cadd(u0,u2); yy[2]=csub(u0,u2);
    if (S < 0) { yy[1]=csub(u1,iu3); yy[3]=cadd(u1,iu3); }
    else       { yy[1]=cadd(u1,iu3); yy[3]=csub(u1,iu3); }
    #pragma unroll
    for (int c0 = 0; c0 < 4; ++c0) {
      const int p = (b0*c0) & 15;
      c32 w = mkc(C16[p], (S<0) ? -S16[p] : S16[p]);
      s[c0*4 + b0] = cmul(yy[c0], w);
    }
  }
  #pragma unroll
  for (int c0 = 0; c0 < 4; ++c0) {
    c32 x0=s[c0*4+0], x1=s[c0*4+1], x2=s[c0*4+2], x3=s[c0*4+3];
    c32 u0=cadd(x0,x2), u1=csub(x0,x2), u2=cadd(x1,x3), u3=csub(x1,x3);
    c32 iu3 = mkc(-u3.y, u3.x);
    c32 yy[4];
    yy[0]=cadd(u0,u2); yy[2]=csub(u0,u2);
    if (S < 0) { yy[1]=csub(u1,iu3); yy[3]=cadd(u1,iu3); }
    else       { yy[1]=cadd(u1,iu3); yy[3]=csub(u1,iu3); }
    v[c0+0]=yy[0]; v[c0+4]=yy[1]; v[c0+8]=yy[2]; v[c0+12]=yy[3];
  }
}

// ------------- 256-pt FFT, 16-thread team, SoA + XOR-swizzled LDS ---------
// storage map: addr(row,col) = row*256 + (col ^ ((row&3)<<3))
// write (fixed c): banks {(16r+t)%32} -> 2-way (free)
// read  (fixed a): banks {((16a+t)^(8(r&3)))%32} -> 2-way (free)
template<int S>
__device__ __forceinline__ void fft256_team(c32 v[16], int r, int t,
                                            float* sre, float* sim) {
  fft16<S>(v);
  float ang = (float)S * (2.0f*PI_F/256.0f) * (float)r;
  c32 st; __sincosf(ang, &st.y, &st.x);
  c32 w = st;
  #pragma unroll
  for (int c = 1; c < 16; ++c) { v[c] = cmul(v[c], w); w = cmul(w, st); }
  __syncthreads();
  #pragma unroll
  for (int c = 0; c < 16; ++c) {
    int idx = c*256 + ((r*16 + t) ^ ((c & 3) << 3));
    sre[idx] = v[c].x; sim[idx] = v[c].y;
  }
  __syncthreads();
  #pragma unroll
  for (int a = 0; a < 16; ++a) {
    int idx = r*256 + ((a*16 + t) ^ ((r & 3) << 3));
    v[a] = mkc(sre[idx], sim[idx]);
  }
  fft16<S>(v);
}

// ---------------- prep: mod_depth, pm, spectral line table ----------------
__global__ __launch_bounds__(256) void k_prep(const float* __restrict__ b1,
    const float* __restrict__ W2, const float* __restrict__ b2,
    const float* __restrict__ W3, const float* __restrict__ b3,
    const float* __restrict__ hp, const float* __restrict__ fw,
    float* __restrict__ pm_out, int* __restrict__ hidx, float* __restrict__ amp) {
  __shared__ float red[256];
  __shared__ float s_md, s_pm;
  int t = threadIdx.x;
  if (t == 0) {
    float h1[32], h2[16];
    for (int i=0;i<32;i++){ float z = b1[i]; h1[i] = z > 0.f ? z : 0.f; }
    for (int o=0;o<16;o++){ float acc = b2[o];
      for (int i=0;i<32;i++) acc += h1[i]*W2[i*16+o];
      h2[o] = acc > 0.f ? acc : 0.f; }
    float md = b3[1];
    for (int i=0;i<16;i++) md += h2[i]*W3[i*8+1];
    s_md = md;
  }
  __syncthreads();
  float md = s_md;
  float partial = 0.f;
  for (int tt = t; tt < 65537; tt += 256) {
    int ci = (tt * 8) / 65537;
    float cs = hp[ci*4+0] + hp[ci*4+1] + hp[ci*4+2] + hp[ci*4+3];
    float ang = (6.2831853071795864769f * (float)tt) / 65537.0f;
    partial += cs * (1.f + md * sinf(ang));
  }
  red[t] = partial;
  __syncthreads();
  for (int s = 128; s > 0; s >>= 1) { if (t < s) red[t] += red[t+s]; __syncthreads(); }
  if (t == 0) { s_pm = red[0] / (65537.0f * 4.0f); pm_out[0] = s_pm; }
  __syncthreads();
  if (t < 40) {
    const double SPECF[8] = {7.83, 528.0, 396.0, 2.5, 14.1, 432.0, 6.0, 30.0};
    int j = t / 5, mi = t % 5;
    double mult = (double)(mi + 1);
    double hf = SPECF[j] * mult;
    double ratio = hf * (131072.0 / 22050.0);
    hidx[t] = (int)floor(ratio + 0.5);
    amp[t] = (float)((double)fw[j] * pow(mult, -1.2) * (1.0 + (double)s_pm));
  }
}

// -------- gain curve + half-twiddle table tw[k] = e^{-i pi k/65536} -------
__global__ __launch_bounds__(256) void k_gain(float* __restrict__ gain,
    c32* __restrict__ tw, const float* __restrict__ bw,
    const int* __restrict__ hidx, const float* __restrict__ amp) {
  int i = blockIdx.x*256 + threadIdx.x;
  if (i >= 65537) return;
  float f = (float)((double)i * (22050.0/131072.0));
  float g = 1.0f;
  constexpr double LO[6] = {1,4,8,13,30,100};
  constexpr double HI[6] = {4,8,13,30,100,200};
  #pragma unroll
  for (int k = 0; k < 6; ++k) {
    float center = (float)(0.5*(LO[k]+HI[k]));
    float sig    = (float)(0.25*(HI[k]-LO[k]));
    float dm = (f - center)/sig;
    float mask = expf(-0.5f*dm*dm);
    if (f < (float)LO[k] || f > (float)HI[k]) mask = 0.f;
    float ang = (float)(6.283185307179586*0.5*(LO[k]+HI[k])) * (float)i / 22050.0f;
    g *= 1.0f + mask * bw[k] * (1.0f + 0.2f*sinf(ang));
  }
  for (int l = 0; l < 40; ++l) {
    int d = i - hidx[l];
    if (d >= -15 && d <= 15) {
      float dd = (float)d * 0.2f;
      g *= 1.0f + amp[l] * expf(-0.5f*dd*dd);
    }
  }
  gain[i] = g;
  float sw, cw;
  sincosf(-(PI_F/65536.0f) * (float)i, &sw, &cw);
  tw[i] = mkc(cw, sw);
}

// ---------------- forward pass 1: pack + column FFT + 4-step twiddle ------
__global__ __launch_bounds__(256) void k_fwd1(const float* __restrict__ x,
                                              c32* __restrict__ A, int s0) {
  __shared__ float sre[4096], sim[4096];
  int b = blockIdx.x; int sl = b >> 4; int g = b & 15;
  int t = threadIdx.x & 15, r = threadIdx.x >> 4;
  int n1 = g*16 + t;
  const float* xb = x + (size_t)(s0 + sl) * L_SIG;
  c32 v[16];
  #pragma unroll
  for (int j = 0; j < 16; ++j) {
    int n = n1 + 256*r + 4096*j;
    c32 z = mkc(0.f, 0.f);
    if (n < 32768)       { z.x = xb[2*n]; z.y = xb[2*n+1]; }
    else if (n == 32768) { z.x = xb[65536]; }
    v[j] = z;
  }
  fft256_team<-1>(v, r, t, sre, sim);
  float a0 = -(2.0f*PI_F/65536.0f) * (float)(n1 * r);
  float a1 = -(2.0f*PI_F/4096.0f)  * (float)n1;
  c32 wb, wst;
  __sincosf(a0, &wb.y, &wb.x);
  __sincosf(a1, &wst.y, &wst.x);
  #pragma unroll
  for (int j = 0; j < 16; ++j) { v[j] = cmul(v[j], wb); wb = cmul(wb, wst); }
  // stage + coalesced store: A[sl][k2*256 + n1]
  __syncthreads();
  #pragma unroll
  for (int j = 0; j < 16; ++j) {
    int idx = (r + 16*j)*16 + t;       // 256j + 16r + t : 2-way banks
    sre[idx] = v[j].x; sim[idx] = v[j].y;
  }
  __syncthreads();
  c32* Ab = A + (size_t)sl * NH;
  int u = threadIdx.x & 15, k2b = threadIdx.x >> 4;
  #pragma unroll
  for (int m = 0; m < 16; ++m) {
    int k2 = k2b + 16*m;
    Ab[(size_t)k2*256 + g*16 + u] = mkc(sre[k2*16 + u], sim[k2*16 + u]);
  }
}

// ---------------- forward pass 2: row FFT -> Z natural order --------------
__global__ __launch_bounds__(256) void k_fwd2(const c32* __restrict__ A,
                                              c32* __restrict__ B) {
  __shared__ float sre[4176], sim[4176];   // stage stride 261; team uses [0,4096)
  int b = blockIdx.x; int sl = b >> 4; int g = b & 15;
  int tid = threadIdx.x;
  int t = tid & 15, r = tid >> 4;
  const c32* Ab = A + (size_t)sl * NH;
  #pragma unroll
  for (int m = 0; m < 8; ++m) {
    int i = tid & 127, row = m*2 + (tid >> 7);
    float4 z = ((const float4*)(Ab + (size_t)(g*16 + row)*256))[i];
    int base = row*261 + 2*i;
    sre[base] = z.x; sim[base] = z.y; sre[base+1] = z.z; sim[base+1] = z.w;
  }
  __syncthreads();
  c32 v[16];
  #pragma unroll
  for (int j = 0; j < 16; ++j) {
    int idx = t*261 + r + 16*j;        // banks (5t+r)%32 : <=2-way
    v[j] = mkc(sre[idx], sim[idx]);
  }
  fft256_team<-1>(v, r, t, sre, sim);
  c32* Bb = B + (size_t)sl * NH;
  int k2 = g*16 + t;
  #pragma unroll
  for (int j = 0; j < 16; ++j) Bb[(size_t)k2 + 256*(r + 16*j)] = v[j];
}

// ---------------- mid: unpack + gain + mag smooth + repack + 1/N ----------
__device__ __forceinline__ c32 unpack_gain(c32 zk, c32 zb, c32 w, float g,
                                           float* mag) {
  // X[k] = 0.5(zk + conj(zb)) - 0.5 i W^k (zk - conj(zb)),  W^k = tw[k]
  c32 Aa = mkc(0.5f*(zk.x + zb.x), 0.5f*(zk.y - zb.y));
  c32 Bm = mkc(0.5f*(zk.x - zb.x), 0.5f*(zk.y + zb.y));
  c32 miw = mkc(w.y, -w.x);               // -i * W^k
  c32 X = cadd(Aa, cmul(miw, Bm));
  X.x *= g; X.y *= g;
  *mag = sqrtf(X.x*X.x + X.y*X.y);
  return X;
}

__global__ __launch_bounds__(256) void k_mid(const c32* __restrict__ Z,
    c32* __restrict__ Zc, const float* __restrict__ gain,
    const c32* __restrict__ tw) {
  __shared__ c32 ZL[258], ZH[258], XL[258], XH[258];
  __shared__ float ML[258], MH[258];
  int b = blockIdx.x; int s = b >> 7; int blk = b & 127;
  int k0 = blk << 8;
  const c32* Zs = Z + (size_t)s * NH;
  c32* Os = Zc + (size_t)s * NH;
  int t = threadIdx.x;
  for (int e = t; e < 258; e += 256) {
    int kl = k0 - 1 + e;
    c32 zl = mkc(0.f,0.f);
    if (kl >= 0) zl = Zs[kl & (NH-1)];
    ZL[e] = zl;
    int kh = NH - k0 - 256 + e;
    ZH[e] = Zs[kh & (NH-1)];
  }
  __syncthreads();
  for (int e = t; e < 258; e += 256) {
    {
      int k = k0 - 1 + e;
      if (k >= 0) { float m; XL[e] = unpack_gain(ZL[e], ZH[257-e], tw[k], gain[k], &m); ML[e] = m; }
      else        { XL[e] = mkc(0.f,0.f); ML[e] = 0.f; }
    }
    {
      int K = NH - k0 - 256 + e;
      if (K <= 65536) { float m; XH[e] = unpack_gain(ZH[e], ZL[257-e], tw[K], gain[K], &m); MH[e] = m; }
      else            { XH[e] = mkc(0.f,0.f); MH[e] = 0.f; }
    }
  }
  __syncthreads();
  {
    int q = t; int k = k0 + q;
    float m = ML[q+1];
    float msm = (k == 0) ? m : 0.7f*m + 0.15f*(ML[q] + ML[q+2]);
    c32 Xl = XL[q+1];
    c32 XcL = (m > 0.f) ? mkc(Xl.x*(msm/m), Xl.y*(msm/m)) : mkc(msm, 0.f);
    int K = NH - k;
    int eH = 256 - q;
    float mh = MH[eH];
    float msh = (K == 65536) ? mh : 0.7f*mh + 0.15f*(MH[eH-1] + MH[eH+1]);
    c32 Xh = XH[eH];
    c32 XcH = (mh > 0.f) ? mkc(Xh.x*(msh/mh), Xh.y*(msh/mh)) : mkc(msh, 0.f);
    // E' = 0.5(XcL + conj(XcH)); O' = 0.5 W^{-k} (XcL - conj(XcH))
    c32 E = mkc(0.5f*(XcL.x + XcH.x), 0.5f*(XcL.y - XcH.y));
    c32 D = mkc(0.5f*(XcL.x - XcH.x), 0.5f*(XcL.y + XcH.y));
    c32 wk = tw[k];                       // conj(tw[k]) = e^{+i pi k/65536}
    float co = wk.x, so = -wk.y;
    c32 O = cmul(mkc(co, so), D);
    const float invN = 1.0f/65536.0f;
    Os[k] = mkc((E.x - O.y)*invN, (E.y + O.x)*invN);              // E' + iO'
    if (k != 0) Os[K] = mkc((E.x + O.y)*invN, (O.x - E.y)*invN);  // conj(E')+i conj(O')
  }
  if (blk == 127 && t == 0) {   // self-paired bin k = 32768
    float m = ML[257];
    float msm = 0.7f*m + 0.15f*(ML[256] + MH[1]);
    c32 Xl = XL[257];
    c32 Xc = (m > 0.f) ? mkc(Xl.x*(msm/m), Xl.y*(msm/m)) : mkc(msm, 0.f);
    const float invN = 1.0f/65536.0f;
    Os[32768] = mkc(Xc.x*invN, -Xc.y*invN);
  }
}

// ---------------- inverse pass 1: column FFT (+) + twiddle ----------------
__global__ __launch_bounds__(256) void k_inv1(const c32* __restrict__ Zc,
                                              c32* __restrict__ B) {
  __shared__ float sre[4096], sim[4096];
  int b = blockIdx.x; int sl = b >> 4; int g = b & 15;
  int t = threadIdx.x & 15, r = threadIdx.x >> 4;
  int a = g*16 + t;
  const c32* Zs = Zc + (size_t)sl * NH;
  c32 v[16];
  #pragma unroll
  for (int j = 0; j < 16; ++j) v[j] = Zs[(size_t)a + 256*(r + 16*j)];
  fft256_team<1>(v, r, t, sre, sim);
  float a0 = (2.0f*PI_F/65536.0f) * (float)(a * r);
  float a1 = (2.0f*PI_F/4096.0f)  * (float)a;
  c32 wb, wst;
  __sincosf(a0, &wb.y, &wb.x);
  __sincosf(a1, &wst.y, &wst.x);
  #pragma unroll
  for (int j = 0; j < 16; ++j) { v[j] = cmul(v[j], wb); wb = cmul(wb, wst); }
  __syncthreads();
  #pragma unroll
  for (int j = 0; j < 16; ++j) {
    int idx = (r + 16*j)*16 + t;
    sre[idx] = v[j].x; sim[idx] = v[j].y;
  }
  __syncthreads();
  c32* Bb = B + (size_t)sl * NH;
  int u = threadIdx.x & 15, m2b = threadIdx.x >> 4;
  #pragma unroll
  for (int m = 0; m < 16; ++m) {
    int m2 = m2b + 16*m;
    Bb[(size_t)m2*256 + g*16 + u] = mkc(sre[m2*16 + u], sim[m2*16 + u]);
  }
}

// ---------------- inverse pass 2: row FFT (+) -> real output --------------
__global__ __launch_bounds__(256) void k_inv2(const c32* __restrict__ B,
                                              float* __restrict__ out, int s0) {
  __shared__ float sre[4176], sim[4176];
  int b = blockIdx.x; int sl = b >> 4; int g = b & 15;
  int tid = threadIdx.x;
  int t = tid & 15, r = tid >> 4;
  const c32* Bb = B + (size_t)sl * NH;
  #pragma unroll
  for (int m = 0; m < 8; ++m) {
    int i = tid & 127, row = m*2 + (tid >> 7);
    float4 z = ((const float4*)(Bb + (size_t)(g*16 + row)*256))[i];
    int base = row*261 + 2*i;
    sre[base] = z.x; sim[base] = z.y; sre[base+1] = z.z; sim[base+1] = z.w;
  }
  __syncthreads();
  c32 v[16];
  #pragma unroll
  for (int j = 0; j < 16; ++j) {
    int idx = t*261 + r + 16*j;
    v[j] = mkc(sre[idx], sim[idx]);
  }
  fft256_team<1>(v, r, t, sre, sim);
  float* yb = out + (size_t)(s0 + sl) * L_SIG;
  int m2 = g*16 + t;
  #pragma unroll
  for (int j = 0; j < 16; ++j) {
    int m1 = r + 16*j;
    if (m1 <= 127) {
      int m = m2 + 256*m1;
      yb[2*m]   = v[j].x;
      yb[2*m+1] = v[j].y;
    } else if (m1 == 128 && m2 == 0) {
      yb[65536] = v[j].x;
    }
  }
}

// --------------------------------------------------------------------------
extern "C" void kernel_launch(void* const* d_in, const int* in_sizes, int n_in,
                              void* d_out, int out_size, void* d_ws, size_t ws_size,
                              hipStream_t stream) {
  const float* x  = (const float*)d_in[0];
  const float* bw = (const float*)d_in[1];
  const float* fw = (const float*)d_in[2];
  const float* hp = (const float*)d_in[3];
  // d_in[4] = W1: mathematically unused (tn==0 at the only sampled row)
  const float* b1 = (const float*)d_in[5];
  const float* W2 = (const float*)d_in[6];
  const float* b2 = (const float*)d_in[7];
  const float* W3 = (const float*)d_in[8];
  const float* b3 = (const float*)d_in[9];
  float* out = (float*)d_out;
  char* ws = (char*)d_ws;

  const size_t perSig = (size_t)NH * sizeof(c32);             // 512 KiB / signal / buffer
  const size_t tail   = (size_t)L_SIG*(sizeof(float)+sizeof(c32)) + 1024;
  size_t cap = (ws_size > tail) ? (ws_size - tail) / (2*perSig) : 1;
  int chunk = (cap >= (size_t)NSIG) ? NSIG : (cap < 1 ? 1 : (int)cap);

  c32*   A    = (c32*)ws;
  c32*   Bb   = (c32*)(ws + (size_t)chunk*perSig);
  c32*   tw   = (c32*)(ws + 2*(size_t)chunk*perSig);
  float* gain = (float*)(tw + L_SIG);
  float* pm   = gain + L_SIG;
  int*   hidx = (int*)(pm + 1);
  float* amp  = (float*)(hidx + 40);

  k_prep<<<1, 256, 0, stream>>>(b1, W2, b2, W3, b3, hp, fw, pm, hidx, amp);
  k_gain<<<257, 256, 0, stream>>>(gain, tw, bw, hidx, amp);

  for (int s0 = 0; s0 < NSIG; s0 += chunk) {
    int S = (NSIG - s0 < chunk) ? (NSIG - s0) : chunk;
    k_fwd1<<<S*16, 256, 0, stream>>>(x, A, s0);
    k_fwd2<<<S*16, 256, 0, stream>>>(A, Bb);
    k_mid <<<S*128,256, 0, stream>>>(Bb, A, gain, tw);
    k_inv1<<<S*16, 256, 0, stream>>>(A, Bb);
    k_inv2<<<S*16, 256, 0, stream>>>(Bb, out, s0);
  }
}

// Round 4
// 349.114 us; speedup vs baseline: 1.3761x; 1.2501x over previous
//
#include <hip/hip_runtime.h>
#include <hip/hip_fp16.h>
#include <math.h>

#define L_SIG 65537
#define NH    65536     // half-size complex FFT length (NFFT/2)
#define NSIG  256
#define PI_F  3.14159265358979323846f

struct c32 { float x, y; };
typedef __half2 h2;
__device__ __forceinline__ c32 mkc(float a, float b){ c32 r; r.x=a; r.y=b; return r; }
__device__ __forceinline__ c32 cadd(c32 a, c32 b){ return mkc(a.x+b.x, a.y+b.y); }
__device__ __forceinline__ c32 csub(c32 a, c32 b){ return mkc(a.x-b.x, a.y-b.y); }
__device__ __forceinline__ c32 cmul(c32 a, c32 b){ return mkc(a.x*b.x - a.y*b.y, a.x*b.y + a.y*b.x); }
__device__ __forceinline__ h2  c2h(c32 a){ return __floats2half2_rn(a.x, a.y); }
__device__ __forceinline__ c32 h2c(h2 a){ float2 f = __half22float2(a); return mkc(f.x, f.y); }

// ---------------- 16-point FFT in registers (radix-4 x 2) ------------------
template<int S>
__device__ __forceinline__ void fft16(c32 v[16]) {
  constexpr float C16[16] = {
    1.0f, 0.9238795325112867f, 0.7071067811865476f, 0.3826834323650898f,
    0.0f,-0.3826834323650898f,-0.7071067811865476f,-0.9238795325112867f,
   -1.0f,-0.9238795325112867f,-0.7071067811865476f,-0.3826834323650898f,
    0.0f, 0.3826834323650898f, 0.7071067811865476f, 0.9238795325112867f };
  constexpr float S16[16] = {
    0.0f, 0.3826834323650898f, 0.7071067811865476f, 0.9238795325112867f,
    1.0f, 0.9238795325112867f, 0.7071067811865476f, 0.3826834323650898f,
    0.0f,-0.3826834323650898f,-0.7071067811865476f,-0.9238795325112867f,
   -1.0f,-0.9238795325112867f,-0.7071067811865476f,-0.3826834323650898f };
  c32 s[16];
  #pragma unroll
  for (int b0 = 0; b0 < 4; ++b0) {
    c32 x0=v[b0], x1=v[b0+4], x2=v[b0+8], x3=v[b0+12];
    c32 u0=cadd(x0,x2), u1=csub(x0,x2), u2=cadd(x1,x3), u3=csub(x1,x3);
    c32 iu3 = mkc(-u3.y, u3.x);
    c32 yy[4];
    yy[0]=cadd(u0,u2); yy[2]=csub(u0,u2);
    if (S < 0) { yy[1]=csub(u1,iu3); yy[3]=cadd(u1,iu3); }
    else       { yy[1]=cadd(u1,iu3); yy[3]=csub(u1,iu3); }
    #pragma unroll
    for (int c0 = 0; c0 < 4; ++c0) {
      const int p = (b0*c0) & 15;
      c32 w = mkc(C16[p], (S<0) ? -S16[p] : S16[p]);
      s[c0*4 + b0] = cmul(yy[c0], w);
    }
  }
  #pragma unroll
  for (int c0 = 0; c0 < 4; ++c0) {
    c32 x0=s[c0*4+0], x1=s[c0*4+1], x2=s[c0*4+2], x3=s[c0*4+3];
    c32 u0=cadd(x0,x2), u1=csub(x0,x2), u2=cadd(x1,x3), u3=csub(x1,x3);
    c32 iu3 = mkc(-u3.y, u3.x);
    c32 yy[4];
    yy[0]=cadd(u0,u2); yy[2]=csub(u0,u2);
    if (S < 0) { yy[1]=csub(u1,iu3); yy[3]=cadd(u1,iu3); }
    else       { yy[1]=cadd(u1,iu3); yy[3]=csub(u1,iu3); }
    v[c0+0]=yy[0]; v[c0+4]=yy[1]; v[c0+8]=yy[2]; v[c0+12]=yy[3];
  }
}

// ------------- 256-pt FFT, 16-thread team, SoA + XOR-swizzled LDS ---------
template<int S>
__device__ __forceinline__ void fft256_team(c32 v[16], int r, int t,
                                            float* sre, float* sim) {
  fft16<S>(v);
  float ang = (float)S * (2.0f*PI_F/256.0f) * (float)r;
  c32 st; __sincosf(ang, &st.y, &st.x);
  c32 w = st;
  #pragma unroll
  for (int c = 1; c < 16; ++c) { v[c] = cmul(v[c], w); w = cmul(w, st); }
  __syncthreads();
  #pragma unroll
  for (int c = 0; c < 16; ++c) {
    int idx = c*256 + ((r*16 + t) ^ ((c & 3) << 3));
    sre[idx] = v[c].x; sim[idx] = v[c].y;
  }
  __syncthreads();
  #pragma unroll
  for (int a = 0; a < 16; ++a) {
    int idx = r*256 + ((a*16 + t) ^ ((r & 3) << 3));
    v[a] = mkc(sre[idx], sim[idx]);
  }
  fft16<S>(v);
}

// ---------------- prep: mod_depth, pm, spectral line table ----------------
__global__ __launch_bounds__(256) void k_prep(const float* __restrict__ b1,
    const float* __restrict__ W2, const float* __restrict__ b2,
    const float* __restrict__ W3, const float* __restrict__ b3,
    const float* __restrict__ hp, const float* __restrict__ fw,
    float* __restrict__ pm_out, int* __restrict__ hidx, float* __restrict__ amp) {
  __shared__ float red[256];
  __shared__ float s_md, s_pm;
  int t = threadIdx.x;
  if (t == 0) {
    float h1[32], h2v[16];
    for (int i=0;i<32;i++){ float z = b1[i]; h1[i] = z > 0.f ? z : 0.f; }
    for (int o=0;o<16;o++){ float acc = b2[o];
      for (int i=0;i<32;i++) acc += h1[i]*W2[i*16+o];
      h2v[o] = acc > 0.f ? acc : 0.f; }
    float md = b3[1];
    for (int i=0;i<16;i++) md += h2v[i]*W3[i*8+1];
    s_md = md;
  }
  __syncthreads();
  float md = s_md;
  float partial = 0.f;
  for (int tt = t; tt < 65537; tt += 256) {
    int ci = (tt * 8) / 65537;
    float cs = hp[ci*4+0] + hp[ci*4+1] + hp[ci*4+2] + hp[ci*4+3];
    float ang = (6.2831853071795864769f * (float)tt) / 65537.0f;
    partial += cs * (1.f + md * sinf(ang));
  }
  red[t] = partial;
  __syncthreads();
  for (int s = 128; s > 0; s >>= 1) { if (t < s) red[t] += red[t+s]; __syncthreads(); }
  if (t == 0) { s_pm = red[0] / (65537.0f * 4.0f); pm_out[0] = s_pm; }
  __syncthreads();
  if (t < 40) {
    const double SPECF[8] = {7.83, 528.0, 396.0, 2.5, 14.1, 432.0, 6.0, 30.0};
    int j = t / 5, mi = t % 5;
    double mult = (double)(mi + 1);
    double hf = SPECF[j] * mult;
    double ratio = hf * (131072.0 / 22050.0);
    hidx[t] = (int)floor(ratio + 0.5);
    amp[t] = (float)((double)fw[j] * pow(mult, -1.2) * (1.0 + (double)s_pm));
  }
}

// ---------------- gain curve: bands + 40 spectral line windows ------------
__global__ __launch_bounds__(256) void k_gain(float* __restrict__ gain,
    const float* __restrict__ bw, const int* __restrict__ hidx,
    const float* __restrict__ amp) {
  int i = blockIdx.x*256 + threadIdx.x;
  if (i >= 65537) return;
  float f = (float)((double)i * (22050.0/131072.0));
  float g = 1.0f;
  constexpr double LO[6] = {1,4,8,13,30,100};
  constexpr double HI[6] = {4,8,13,30,100,200};
  #pragma unroll
  for (int k = 0; k < 6; ++k) {
    float center = (float)(0.5*(LO[k]+HI[k]));
    float sig    = (float)(0.25*(HI[k]-LO[k]));
    float dm = (f - center)/sig;
    float mask = expf(-0.5f*dm*dm);
    if (f < (float)LO[k] || f > (float)HI[k]) mask = 0.f;
    float ang = (float)(6.283185307179586*0.5*(LO[k]+HI[k])) * (float)i / 22050.0f;
    g *= 1.0f + mask * bw[k] * (1.0f + 0.2f*sinf(ang));
  }
  for (int l = 0; l < 40; ++l) {
    int d = i - hidx[l];
    if (d >= -15 && d <= 15) {
      float dd = (float)d * 0.2f;
      g *= 1.0f + amp[l] * expf(-0.5f*dd*dd);
    }
  }
  gain[i] = g;
}

// ---------------- forward pass 1: pack + column FFT + 4-step twiddle ------
__global__ __launch_bounds__(256) void k_fwd1(const float* __restrict__ x,
                                              h2* __restrict__ A, int s0) {
  __shared__ float sre[4096], sim[4096];
  int b = blockIdx.x; int sl = b >> 4; int g = b & 15;
  int t = threadIdx.x & 15, r = threadIdx.x >> 4;
  int n1 = g*16 + t;
  const float* xb = x + (size_t)(s0 + sl) * L_SIG;
  c32 v[16];
  #pragma unroll
  for (int j = 0; j < 16; ++j) {
    int n = n1 + 256*r + 4096*j;
    c32 z = mkc(0.f, 0.f);
    if (n < 32768)       { z.x = xb[2*n]; z.y = xb[2*n+1]; }
    else if (n == 32768) { z.x = xb[65536]; }
    v[j] = z;
  }
  fft256_team<-1>(v, r, t, sre, sim);
  float a0 = -(2.0f*PI_F/65536.0f) * (float)(n1 * r);
  float a1 = -(2.0f*PI_F/4096.0f)  * (float)n1;
  c32 wb, wst;
  __sincosf(a0, &wb.y, &wb.x);
  __sincosf(a1, &wst.y, &wst.x);
  #pragma unroll
  for (int j = 0; j < 16; ++j) { v[j] = cmul(v[j], wb); wb = cmul(wb, wst); }
  // stage + coalesced store: A[sl][k2*256 + n1]
  __syncthreads();
  #pragma unroll
  for (int j = 0; j < 16; ++j) {
    int idx = (r + 16*j)*16 + t;       // 256j + 16r + t : 2-way banks
    sre[idx] = v[j].x; sim[idx] = v[j].y;
  }
  __syncthreads();
  h2* Ab = A + (size_t)sl * NH;
  int u = threadIdx.x & 15, k2b = threadIdx.x >> 4;
  #pragma unroll
  for (int m = 0; m < 16; ++m) {
    int k2 = k2b + 16*m;
    Ab[(size_t)k2*256 + g*16 + u] = c2h(mkc(sre[k2*16 + u], sim[k2*16 + u]));
  }
}

// ---------------- forward pass 2: row FFT -> Z natural order --------------
// stage-in: stg (h2, stride 260) aliases the team-FFT scratch (safe: fragments
// are in registers before fft256_team's first interior barrier).
__global__ __launch_bounds__(256) void k_fwd2(const h2* __restrict__ A,
                                              h2* __restrict__ B) {
  __shared__ float smem[8192];         // 32 KB: stg (16*260 h2) then sre/sim
  h2* stg = (h2*)smem;
  float* sre = smem; float* sim = smem + 4096;
  int b = blockIdx.x; int sl = b >> 4; int g = b & 15;
  int tid = threadIdx.x;
  int t = tid & 15, r = tid >> 4;
  const h2* Ab = A + (size_t)sl * NH;
  #pragma unroll
  for (int m = 0; m < 4; ++m) {
    int flat = tid + 256*m;
    int row = flat >> 6, i = flat & 63;
    float4 z = ((const float4*)(Ab + (size_t)(g*16 + row)*256))[i];
    *((float4*)&stg[row*260 + 4*i]) = z;   // 16B aligned, conflict-free
  }
  __syncthreads();
  c32 v[16];
  #pragma unroll
  for (int j = 0; j < 16; ++j)
    v[j] = h2c(stg[t*260 + r + 16*j]);     // banks (4t+r+16j)%32 : 2-way
  fft256_team<-1>(v, r, t, sre, sim);
  h2* Bb = B + (size_t)sl * NH;
  int k2 = g*16 + t;
  #pragma unroll
  for (int j = 0; j < 16; ++j) Bb[(size_t)k2 + 256*(r + 16*j)] = c2h(v[j]);
}

// ---------------- mid: unpack + gain + mag smooth + repack + 1/N ----------
__device__ __forceinline__ c32 unpack_gain(c32 zk, c32 zb, int k,
                                           const float* __restrict__ gain,
                                           float* mag) {
  // X[k] = 0.5(zk + conj(zb)) - 0.5 i W^k (zk - conj(zb)),  W = e^{-i pi/65536}
  c32 Aa = mkc(0.5f*(zk.x + zb.x), 0.5f*(zk.y - zb.y));
  c32 Bm = mkc(0.5f*(zk.x - zb.x), 0.5f*(zk.y + zb.y));
  float sw, cw; __sincosf(-(PI_F/65536.0f) * (float)k, &sw, &cw);
  c32 miw = mkc(sw, -cw);                 // -i * W^k
  c32 X = cadd(Aa, cmul(miw, Bm));
  float g = gain[k];
  X.x *= g; X.y *= g;
  *mag = sqrtf(X.x*X.x + X.y*X.y);
  return X;
}

__global__ __launch_bounds__(256) void k_mid(const h2* __restrict__ Z,
    h2* __restrict__ Zc, const float* __restrict__ gain) {
  __shared__ c32 ZL[258], ZH[258], XL[258], XH[258];
  __shared__ float ML[258], MH[258];
  int b = blockIdx.x; int s = b >> 7; int blk = b & 127;
  int k0 = blk << 8;
  const h2* Zs = Z + (size_t)s * NH;
  h2* Os = Zc + (size_t)s * NH;
  int t = threadIdx.x;
  for (int e = t; e < 258; e += 256) {
    int kl = k0 - 1 + e;
    c32 zl = mkc(0.f,0.f);
    if (kl >= 0) zl = h2c(Zs[kl & (NH-1)]);
    ZL[e] = zl;
    int kh = NH - k0 - 256 + e;
    ZH[e] = h2c(Zs[kh & (NH-1)]);
  }
  __syncthreads();
  for (int e = t; e < 258; e += 256) {
    {
      int k = k0 - 1 + e;
      if (k >= 0) { float m; XL[e] = unpack_gain(ZL[e], ZH[257-e], k, gain, &m); ML[e] = m; }
      else        { XL[e] = mkc(0.f,0.f); ML[e] = 0.f; }
    }
    {
      int K = NH - k0 - 256 + e;
      if (K <= 65536) { float m; XH[e] = unpack_gain(ZH[e], ZL[257-e], K, gain, &m); MH[e] = m; }
      else            { XH[e] = mkc(0.f,0.f); MH[e] = 0.f; }
    }
  }
  __syncthreads();
  {
    int q = t; int k = k0 + q;
    float m = ML[q+1];
    float msm = (k == 0) ? m : 0.7f*m + 0.15f*(ML[q] + ML[q+2]);
    c32 Xl = XL[q+1];
    c32 XcL = (m > 0.f) ? mkc(Xl.x*(msm/m), Xl.y*(msm/m)) : mkc(msm, 0.f);
    int K = NH - k;
    int eH = 256 - q;
    float mh = MH[eH];
    float msh = (K == 65536) ? mh : 0.7f*mh + 0.15f*(MH[eH-1] + MH[eH+1]);
    c32 Xh = XH[eH];
    c32 XcH = (mh > 0.f) ? mkc(Xh.x*(msh/mh), Xh.y*(msh/mh)) : mkc(msh, 0.f);
    // E' = 0.5(XcL + conj(XcH)); O' = 0.5 W^{-k} (XcL - conj(XcH))
    c32 E = mkc(0.5f*(XcL.x + XcH.x), 0.5f*(XcL.y - XcH.y));
    c32 D = mkc(0.5f*(XcL.x - XcH.x), 0.5f*(XcL.y + XcH.y));
    float so, co; __sincosf((PI_F/65536.0f)*(float)k, &so, &co);
    c32 O = cmul(mkc(co, so), D);
    const float invN = 1.0f/65536.0f;
    Os[k] = c2h(mkc((E.x - O.y)*invN, (E.y + O.x)*invN));              // E' + iO'
    if (k != 0) Os[K] = c2h(mkc((E.x + O.y)*invN, (O.x - E.y)*invN));  // conj pack
  }
  if (blk == 127 && t == 0) {   // self-paired bin k = 32768
    float m = ML[257];
    float msm = 0.7f*m + 0.15f*(ML[256] + MH[1]);
    c32 Xl = XL[257];
    c32 Xc = (m > 0.f) ? mkc(Xl.x*(msm/m), Xl.y*(msm/m)) : mkc(msm, 0.f);
    const float invN = 1.0f/65536.0f;
    Os[32768] = c2h(mkc(Xc.x*invN, -Xc.y*invN));
  }
}

// ---------------- inverse pass 1: column FFT (+) + twiddle ----------------
__global__ __launch_bounds__(256) void k_inv1(const h2* __restrict__ Zc,
                                              h2* __restrict__ B) {
  __shared__ float sre[4096], sim[4096];
  int b = blockIdx.x; int sl = b >> 4; int g = b & 15;
  int t = threadIdx.x & 15, r = threadIdx.x >> 4;
  int a = g*16 + t;
  const h2* Zs = Zc + (size_t)sl * NH;
  c32 v[16];
  #pragma unroll
  for (int j = 0; j < 16; ++j) v[j] = h2c(Zs[(size_t)a + 256*(r + 16*j)]);
  fft256_team<1>(v, r, t, sre, sim);
  float a0 = (2.0f*PI_F/65536.0f) * (float)(a * r);
  float a1 = (2.0f*PI_F/4096.0f)  * (float)a;
  c32 wb, wst;
  __sincosf(a0, &wb.y, &wb.x);
  __sincosf(a1, &wst.y, &wst.x);
  #pragma unroll
  for (int j = 0; j < 16; ++j) { v[j] = cmul(v[j], wb); wb = cmul(wb, wst); }
  __syncthreads();
  #pragma unroll
  for (int j = 0; j < 16; ++j) {
    int idx = (r + 16*j)*16 + t;
    sre[idx] = v[j].x; sim[idx] = v[j].y;
  }
  __syncthreads();
  h2* Bb = B + (size_t)sl * NH;
  int u = threadIdx.x & 15, m2b = threadIdx.x >> 4;
  #pragma unroll
  for (int m = 0; m < 16; ++m) {
    int m2 = m2b + 16*m;
    Bb[(size_t)m2*256 + g*16 + u] = c2h(mkc(sre[m2*16 + u], sim[m2*16 + u]));
  }
}

// ---------------- inverse pass 2: row FFT (+) -> real output --------------
__global__ __launch_bounds__(256) void k_inv2(const h2* __restrict__ B,
                                              float* __restrict__ out, int s0) {
  __shared__ float smem[8192];
  h2* stg = (h2*)smem;
  float* sre = smem; float* sim = smem + 4096;
  int b = blockIdx.x; int sl = b >> 4; int g = b & 15;
  int tid = threadIdx.x;
  int t = tid & 15, r = tid >> 4;
  const h2* Bb = B + (size_t)sl * NH;
  #pragma unroll
  for (int m = 0; m < 4; ++m) {
    int flat = tid + 256*m;
    int row = flat >> 6, i = flat & 63;
    float4 z = ((const float4*)(Bb + (size_t)(g*16 + row)*256))[i];
    *((float4*)&stg[row*260 + 4*i]) = z;
  }
  __syncthreads();
  c32 v[16];
  #pragma unroll
  for (int j = 0; j < 16; ++j)
    v[j] = h2c(stg[t*260 + r + 16*j]);
  fft256_team<1>(v, r, t, sre, sim);
  float* yb = out + (size_t)(s0 + sl) * L_SIG;
  int m2 = g*16 + t;
  #pragma unroll
  for (int j = 0; j < 16; ++j) {
    int m1 = r + 16*j;
    if (m1 <= 127) {
      int m = m2 + 256*m1;
      yb[2*m]   = v[j].x;
      yb[2*m+1] = v[j].y;
    } else if (m1 == 128 && m2 == 0) {
      yb[65536] = v[j].x;
    }
  }
}

// --------------------------------------------------------------------------
extern "C" void kernel_launch(void* const* d_in, const int* in_sizes, int n_in,
                              void* d_out, int out_size, void* d_ws, size_t ws_size,
                              hipStream_t stream) {
  const float* x  = (const float*)d_in[0];
  const float* bw = (const float*)d_in[1];
  const float* fw = (const float*)d_in[2];
  const float* hp = (const float*)d_in[3];
  // d_in[4] = W1: mathematically unused (tn==0 at the only sampled row)
  const float* b1 = (const float*)d_in[5];
  const float* W2 = (const float*)d_in[6];
  const float* b2 = (const float*)d_in[7];
  const float* W3 = (const float*)d_in[8];
  const float* b3 = (const float*)d_in[9];
  float* out = (float*)d_out;
  char* ws = (char*)d_ws;

  const size_t perSig = (size_t)NH * sizeof(h2);              // 256 KiB / signal / buffer
  const size_t tail   = (size_t)L_SIG * sizeof(float) + 1024; // gain + scalars
  size_t cap = (ws_size > tail) ? (ws_size - tail) / (2*perSig) : 1;
  int chunk = (cap >= (size_t)NSIG) ? NSIG : (cap < 1 ? 1 : (int)cap);

  h2*    A    = (h2*)ws;
  h2*    Bb   = (h2*)(ws + (size_t)chunk*perSig);
  float* gain = (float*)(ws + 2*(size_t)chunk*perSig);
  float* pm   = gain + L_SIG;
  int*   hidx = (int*)(pm + 1);
  float* amp  = (float*)(hidx + 40);

  k_prep<<<1, 256, 0, stream>>>(b1, W2, b2, W3, b3, hp, fw, pm, hidx, amp);
  k_gain<<<257, 256, 0, stream>>>(gain, bw, hidx, amp);

  for (int s0 = 0; s0 < NSIG; s0 += chunk) {
    int S = (NSIG - s0 < chunk) ? (NSIG - s0) : chunk;
    k_fwd1<<<S*16, 256, 0, stream>>>(x, A, s0);
    k_fwd2<<<S*16, 256, 0, stream>>>(A, Bb);
    k_mid <<<S*128,256, 0, stream>>>(Bb, A, gain);
    k_inv1<<<S*16, 256, 0, stream>>>(A, Bb);
    k_inv2<<<S*16, 256, 0, stream>>>(Bb, out, s0);
  }
}